// Round 3
// baseline (292.796 us; speedup 1.0000x reference)
//
#include <hip/hip_runtime.h>

#define N_NODES 10000
#define BATCH   8
#define IN_SZ   64
#define UNITS   64
#define WIDTH   512            // IN_SZ * BATCH (bf16 elements per node row)
#define ROW_U   256            // uints per bf16 row (512 bf16)

typedef unsigned int uint;
typedef __attribute__((ext_vector_type(8))) short short8;
typedef __attribute__((ext_vector_type(4))) float float4v;

// ---- bf16 helpers (RNE) ----------------------------------------------------
__device__ inline float bf_lo(uint u) { return __uint_as_float(u << 16); }
__device__ inline float bf_hi(uint u) { return __uint_as_float(u & 0xFFFF0000u); }
__device__ inline uint  f2bf_bits(float f) {
    uint u = __float_as_uint(f);
    uint r = ((u >> 16) & 1u) + 0x7FFFu;
    return (u + r) >> 16;
}
__device__ inline uint pack2(float a, float b) {
    return f2bf_bits(a) | (f2bf_bits(b) << 16);
}

// ---------------------------------------------------------------------------
// k_transpose: in[b, n*64+i] (fp32) -> x0[n, b*64+i] (bf16). With the b*64+i
// column order this is a pure copy: both read and write fully coalesced,
// no LDS. Thread owns one packed uint (2 consecutive i). Also zeroes counts.
// ---------------------------------------------------------------------------
__global__ __launch_bounds__(256) void k_transpose(const float2* __restrict__ in2,
                                                   uint* __restrict__ x0,
                                                   int* __restrict__ counts) {
    int gid = blockIdx.x * 256 + threadIdx.x;      // uint index, 2,560,000 total
    if (gid < N_NODES) counts[gid] = 0;
    int n  = gid >> 8;          // /256 uints per row
    int b  = (gid >> 5) & 7;    // 32 uints per (n,b) chunk
    int iu = gid & 31;
    float2 v = in2[(size_t)b * (N_NODES * 32) + (size_t)n * 32 + iu];
    x0[gid] = pack2(v.x, v.y);
}

// ---------------------------------------------------------------------------
// k_hist: row histogram for CSR build.
// ---------------------------------------------------------------------------
__global__ __launch_bounds__(256) void k_hist(const int* __restrict__ rows,
                                              int* __restrict__ counts, int nnz) {
    int e = blockIdx.x * 256 + threadIdx.x;
    if (e < nnz) atomicAdd(&counts[rows[e]], 1);
}

// ---------------------------------------------------------------------------
// k_scan: single block, 256 threads, serial chunk + wave shfl-scan.
// Zeroes counts for reuse as scatter cursors.
// ---------------------------------------------------------------------------
#define CHUNK 40
__global__ __launch_bounds__(256) void k_scan(int* __restrict__ counts,
                                              int* __restrict__ row_ptr, int n) {
    __shared__ int wsum[4];
    int t    = threadIdx.x;
    int base = t * CHUNK;
    int local[CHUNK];
    int tot = 0;
#pragma unroll
    for (int j = 0; j < CHUNK; ++j) {
        int idx = base + j;
        int v   = (idx < n) ? counts[idx] : 0;
        if (idx < n) counts[idx] = 0;
        local[j] = v;
        tot += v;
    }
    int lane = t & 63, w = t >> 6;
    int s = tot;
#pragma unroll
    for (int off = 1; off < 64; off <<= 1) {
        int nv = __shfl_up(s, off);
        if (lane >= off) s += nv;
    }
    if (lane == 63) wsum[w] = s;
    __syncthreads();
    int woff = 0;
    for (int k = 0; k < 4; ++k) if (k < w) woff += wsum[k];
    int run = woff + s - tot;
#pragma unroll
    for (int j = 0; j < CHUNK; ++j) {
        int idx = base + j;
        if (idx < n) row_ptr[idx] = run;
        run += local[j];
    }
    if (t == 255) row_ptr[n] = woff + s;
}

// ---------------------------------------------------------------------------
// k_scatter: scatter COO edges into CSR order.
// ---------------------------------------------------------------------------
__global__ __launch_bounds__(256) void k_scatter(const int* __restrict__ rows,
                                                 const int* __restrict__ cols,
                                                 const float* __restrict__ vals,
                                                 const int* __restrict__ row_ptr,
                                                 int* __restrict__ cursor,
                                                 int* __restrict__ cols_s,
                                                 float* __restrict__ vals_s, int nnz) {
    int e = blockIdx.x * 256 + threadIdx.x;
    if (e >= nnz) return;
    int r   = rows[e];
    int pos = row_ptr[r] + atomicAdd(&cursor[r], 1);
    cols_s[pos] = cols[e];
    vals_s[pos] = vals[e];
}

// ---------------------------------------------------------------------------
// k_spmm: one WAVE per (row, column-quarter). blockIdx.y = quarter so all
// same-quarter blocks run temporally adjacent -> per-quarter working set is
// 10000*256B = 2.5 MB, resident in each XCD's 4 MiB L2. No barriers; edge
// (col,val) broadcast via readlane. Gather per edge = 256B contiguous.
// ---------------------------------------------------------------------------
__global__ __launch_bounds__(256) void k_spmm(const int* __restrict__ row_ptr,
                                              const int* __restrict__ cols_s,
                                              const float* __restrict__ vals_s,
                                              const uint* __restrict__ xin,
                                              uint* __restrict__ xout,
                                              const uint* __restrict__ xsub,
                                              float scale) {
    int wave = threadIdx.x >> 6;
    int lane = threadIdx.x & 63;
    int row  = blockIdx.x * 4 + wave;
    int q    = blockIdx.y;
    int col_u = q * 64 + lane;                 // uint column this lane owns

    int start = row_ptr[row];
    int end   = row_ptr[row + 1];
    float ax = 0.f, ay = 0.f;
    for (int base = start; base < end; base += 64) {
        int e = base + lane;
        int c = 0; float v = 0.f;
        if (e < end) { c = cols_s[e]; v = vals_s[e]; }
        int cnt = end - base; if (cnt > 64) cnt = 64;
        for (int j = 0; j < cnt; ++j) {
            int   cj = __builtin_amdgcn_readlane(c, j);
            float vj = __uint_as_float(__builtin_amdgcn_readlane(__float_as_uint(v), j));
            uint  x  = xin[(size_t)cj * ROW_U + col_u];
            ax += vj * bf_lo(x);
            ay += vj * bf_hi(x);
        }
    }
    float ox = scale * ax, oy = scale * ay;
    if (xsub) {
        uint sx = xsub[(size_t)row * ROW_U + col_u];
        ox -= bf_lo(sx);
        oy -= bf_hi(sx);
    }
    xout[(size_t)row * ROW_U + col_u] = pack2(ox, oy);
}

// ---------------------------------------------------------------------------
// k_combine (MFMA): out[b,n,u] = bias[u] + sum_k A[(b,n), k] * Wp[k, u]
// with k = mat*64 + i, A[(b,n), k] = T_mat[n, b*64+i] (bf16, contiguous in i).
// Block = 4 waves; wave w owns 16 nodes (n0 = blk*64 + w*16) x 64 units,
// loops b = 0..7. W transposed to LDS as bf16 [u][k] (k padded 192->200).
// A frags load direct from L2-hot x arrays as 16B short8.
// 16x16x32 bf16 MFMA: A[m=lane&15][k=quad*8+j]; B[k=quad*8+j][n=lane&15];
// C col=lane&15, row=quad*4+reg.
// ---------------------------------------------------------------------------
__global__ __launch_bounds__(256) void k_combine(const uint* __restrict__ x0,
                                                 const uint* __restrict__ x1,
                                                 const uint* __restrict__ x2,
                                                 const float* __restrict__ W,
                                                 const float* __restrict__ bias,
                                                 float* __restrict__ out) {
    __shared__ unsigned short sWt[64][200];    // [u][k] bf16, pad 192->200 (25.6 KB)
    int t = threadIdx.x;
    for (int e = t; e < 192 * 64; e += 256) {
        int f = e >> 6;                        // fan_in row = i*3 + m
        int u = e & 63;
        int i = f / 3;
        int m = f - 3 * i;
        sWt[u][m * 64 + i] = (unsigned short)f2bf_bits(W[e]);
    }
    __syncthreads();

    int wave = t >> 6, lane = t & 63;
    int mrow = lane & 15, quad = lane >> 4;
    int n0   = blockIdx.x * 64 + wave * 16;

    // B fragments: 6 k-blocks x 4 u-tiles, loaded once, reused for all 8 b.
    short8 bfrag[6][4];
#pragma unroll
    for (int kb = 0; kb < 6; ++kb)
#pragma unroll
        for (int ut = 0; ut < 4; ++ut)
            bfrag[kb][ut] = *(const short8*)&sWt[ut * 16 + mrow][kb * 32 + quad * 8];

    float bv[4];
#pragma unroll
    for (int ut = 0; ut < 4; ++ut) bv[ut] = bias[ut * 16 + mrow];

    const uint* xs[3] = {x0, x1, x2};
    int an = n0 + mrow;                        // node this lane's A row covers

    for (int b = 0; b < 8; ++b) {
        float4v acc[4];
#pragma unroll
        for (int ut = 0; ut < 4; ++ut) acc[ut] = (float4v){0.f, 0.f, 0.f, 0.f};

#pragma unroll
        for (int kb = 0; kb < 6; ++kb) {
            int mat = kb >> 1;
            int i0  = (kb & 1) * 32;
            // uint offset: (b*64 + i0 + quad*8) bf16 -> /2
            const short8* ap =
                (const short8*)(xs[mat] + (size_t)an * ROW_U + b * 32 + i0 / 2 + quad * 4);
            short8 af = *ap;
#pragma unroll
            for (int ut = 0; ut < 4; ++ut)
                acc[ut] = __builtin_amdgcn_mfma_f32_16x16x32_bf16(af, bfrag[kb][ut],
                                                                  acc[ut], 0, 0, 0);
        }

#pragma unroll
        for (int ut = 0; ut < 4; ++ut) {
            int u = ut * 16 + mrow;
#pragma unroll
            for (int r = 0; r < 4; ++r) {
                int n = n0 + quad * 4 + r;
                if (n < N_NODES)
                    out[((size_t)b * N_NODES + n) * UNITS + u] = acc[ut][r] + bv[ut];
            }
        }
    }
}

// ---------------------------------------------------------------------------
extern "C" void kernel_launch(void* const* d_in, const int* in_sizes, int n_in,
                              void* d_out, int out_size, void* d_ws, size_t ws_size,
                              hipStream_t stream) {
    const float* inputs = (const float*)d_in[0];
    const int*   rows   = (const int*)d_in[1];
    const int*   cols   = (const int*)d_in[2];
    const float* vals   = (const float*)d_in[3];
    const float* W      = (const float*)d_in[4];
    const float* bias   = (const float*)d_in[5];
    float*       out    = (float*)d_out;
    int nnz = in_sizes[1];

    char* p = (char*)d_ws;
    auto alloc = [&](size_t bytes) {
        char* r = p;
        p += (bytes + 255) & ~(size_t)255;
        return r;
    };
    uint*  x0      = (uint*)alloc(sizeof(uint) * (size_t)N_NODES * ROW_U);
    uint*  x1      = (uint*)alloc(sizeof(uint) * (size_t)N_NODES * ROW_U);
    uint*  x2      = (uint*)alloc(sizeof(uint) * (size_t)N_NODES * ROW_U);
    int*   row_ptr = (int*)alloc(sizeof(int) * (N_NODES + 1));
    int*   cursor  = (int*)alloc(sizeof(int) * N_NODES);
    int*   cols_s  = (int*)alloc(sizeof(int) * (size_t)nnz);
    float* vals_s  = (float*)alloc(sizeof(float) * (size_t)nnz);

    k_transpose<<<N_NODES, 256, 0, stream>>>((const float2*)inputs, x0, cursor);
    k_hist<<<(nnz + 255) / 256, 256, 0, stream>>>(rows, cursor, nnz);
    k_scan<<<1, 256, 0, stream>>>(cursor, row_ptr, N_NODES);
    k_scatter<<<(nnz + 255) / 256, 256, 0, stream>>>(rows, cols, vals, row_ptr, cursor,
                                                     cols_s, vals_s, nnz);
    dim3 sgrid(N_NODES / 4, 4);
    k_spmm<<<sgrid, 256, 0, stream>>>(row_ptr, cols_s, vals_s, x0, x1, nullptr, 1.0f);
    k_spmm<<<sgrid, 256, 0, stream>>>(row_ptr, cols_s, vals_s, x1, x2, x0, 2.0f);
    k_combine<<<(N_NODES + 63) / 64, 256, 0, stream>>>(x0, x1, x2, W, bias, out);
}

// Round 4
// 223.163 us; speedup vs baseline: 1.3120x; 1.3120x over previous
//
#include <hip/hip_runtime.h>

#define N_NODES 10000
#define BATCH   8
#define IN_SZ   64
#define UNITS   64
#define WIDTH   512            // IN_SZ * BATCH (bf16 elements per node row)
#define ROW_U   256            // uints per bf16 row (512 bf16)
#define ROW_U2  128            // uint2 per bf16 row

typedef unsigned int uint;
typedef __attribute__((ext_vector_type(8))) short short8;
typedef __attribute__((ext_vector_type(4))) float float4v;

// ---- bf16 helpers (RNE) ----------------------------------------------------
__device__ inline float bf_lo(uint u) { return __uint_as_float(u << 16); }
__device__ inline float bf_hi(uint u) { return __uint_as_float(u & 0xFFFF0000u); }
__device__ inline uint  f2bf_bits(float f) {
    uint u = __float_as_uint(f);
    uint r = ((u >> 16) & 1u) + 0x7FFFu;
    return (u + r) >> 16;
}
__device__ inline uint pack2(float a, float b) {
    return f2bf_bits(a) | (f2bf_bits(b) << 16);
}
__device__ inline float rl_f(float v, int j) {
    return __uint_as_float(__builtin_amdgcn_readlane(__float_as_uint(v), j));
}

// ---------------------------------------------------------------------------
// k_transpose: in[b, n*64+i] (fp32) -> x0[n, b*64+i] (bf16) — pure coalesced
// copy, no LDS. Also zeroes the CSR count array.
// ---------------------------------------------------------------------------
__global__ __launch_bounds__(256) void k_transpose(const float2* __restrict__ in2,
                                                   uint* __restrict__ x0,
                                                   int* __restrict__ counts) {
    int gid = blockIdx.x * 256 + threadIdx.x;      // uint index, 2,560,000 total
    if (gid < N_NODES) counts[gid] = 0;
    int n  = gid >> 8;          // /256 uints per row
    int b  = (gid >> 5) & 7;    // 32 uints per (n,b) chunk
    int iu = gid & 31;
    float2 v = in2[(size_t)b * (N_NODES * 32) + (size_t)n * 32 + iu];
    x0[gid] = pack2(v.x, v.y);
}

// ---------------------------------------------------------------------------
// k_hist: row histogram for CSR build.
// ---------------------------------------------------------------------------
__global__ __launch_bounds__(256) void k_hist(const int* __restrict__ rows,
                                              int* __restrict__ counts, int nnz) {
    int e = blockIdx.x * 256 + threadIdx.x;
    if (e < nnz) atomicAdd(&counts[rows[e]], 1);
}

// ---------------------------------------------------------------------------
// k_scan: single block, 256 threads, serial chunk + wave shfl-scan.
// Zeroes counts for reuse as scatter cursors.
// ---------------------------------------------------------------------------
#define CHUNK 40
__global__ __launch_bounds__(256) void k_scan(int* __restrict__ counts,
                                              int* __restrict__ row_ptr, int n) {
    __shared__ int wsum[4];
    int t    = threadIdx.x;
    int base = t * CHUNK;
    int local[CHUNK];
    int tot = 0;
#pragma unroll
    for (int j = 0; j < CHUNK; ++j) {
        int idx = base + j;
        int v   = (idx < n) ? counts[idx] : 0;
        if (idx < n) counts[idx] = 0;
        local[j] = v;
        tot += v;
    }
    int lane = t & 63, w = t >> 6;
    int s = tot;
#pragma unroll
    for (int off = 1; off < 64; off <<= 1) {
        int nv = __shfl_up(s, off);
        if (lane >= off) s += nv;
    }
    if (lane == 63) wsum[w] = s;
    __syncthreads();
    int woff = 0;
    for (int k = 0; k < 4; ++k) if (k < w) woff += wsum[k];
    int run = woff + s - tot;
#pragma unroll
    for (int j = 0; j < CHUNK; ++j) {
        int idx = base + j;
        if (idx < n) row_ptr[idx] = run;
        run += local[j];
    }
    if (t == 255) row_ptr[n] = woff + s;
}

// ---------------------------------------------------------------------------
// k_scatter: scatter COO edges into CSR order.
// ---------------------------------------------------------------------------
__global__ __launch_bounds__(256) void k_scatter(const int* __restrict__ rows,
                                                 const int* __restrict__ cols,
                                                 const float* __restrict__ vals,
                                                 const int* __restrict__ row_ptr,
                                                 int* __restrict__ cursor,
                                                 int* __restrict__ cols_s,
                                                 float* __restrict__ vals_s, int nnz) {
    int e = blockIdx.x * 256 + threadIdx.x;
    if (e >= nnz) return;
    int r   = rows[e];
    int pos = row_ptr[r] + atomicAdd(&cursor[r], 1);
    cols_s[pos] = cols[e];
    vals_s[pos] = vals[e];
}

// ---------------------------------------------------------------------------
// k_spmm: one WAVE per (row, column-half). Lane owns a uint2 (4 bf16 cols).
// Edge (col,val) lists zero-padded to a multiple of 4 so the gather loop is
// hand-unrolled x4: 4 independent global_load_dwordx2 in flight per group,
// row bases via readlane->SALU. blockIdx.y = half keeps the per-stripe
// working set (~5 MB) mostly L2-resident and groups blocks temporally.
// ---------------------------------------------------------------------------
__global__ __launch_bounds__(256) void k_spmm(const int* __restrict__ row_ptr,
                                              const int* __restrict__ cols_s,
                                              const float* __restrict__ vals_s,
                                              const uint2* __restrict__ xin,
                                              uint2* __restrict__ xout,
                                              const uint2* __restrict__ xsub,
                                              float scale) {
    int wave = threadIdx.x >> 6;
    int lane = threadIdx.x & 63;
    int row  = blockIdx.x * 4 + wave;
    int col2 = blockIdx.y * 64 + lane;         // uint2 column (of 128 per row)

    int start = row_ptr[row];
    int end   = row_ptr[row + 1];
    float a0 = 0.f, a1 = 0.f, a2 = 0.f, a3 = 0.f;

    for (int base = start; base < end; base += 64) {
        int e = base + lane;
        int c = 0; float v = 0.f;
        if (e < end) { c = cols_s[e]; v = vals_s[e]; }   // pad: c=0, v=0
        int cnt = min(64, end - base);
        cnt = (cnt + 3) & ~3;                  // zero-padded groups of 4
        for (int j = 0; j < cnt; j += 4) {
            int   c0 = __builtin_amdgcn_readlane(c, j);
            int   c1 = __builtin_amdgcn_readlane(c, j + 1);
            int   c2 = __builtin_amdgcn_readlane(c, j + 2);
            int   c3 = __builtin_amdgcn_readlane(c, j + 3);
            float v0 = rl_f(v, j);
            float v1 = rl_f(v, j + 1);
            float v2 = rl_f(v, j + 2);
            float v3 = rl_f(v, j + 3);
            uint2 x0 = xin[(size_t)c0 * ROW_U2 + col2];
            uint2 x1 = xin[(size_t)c1 * ROW_U2 + col2];
            uint2 x2 = xin[(size_t)c2 * ROW_U2 + col2];
            uint2 x3 = xin[(size_t)c3 * ROW_U2 + col2];
            a0 += v0 * bf_lo(x0.x); a1 += v0 * bf_hi(x0.x);
            a2 += v0 * bf_lo(x0.y); a3 += v0 * bf_hi(x0.y);
            a0 += v1 * bf_lo(x1.x); a1 += v1 * bf_hi(x1.x);
            a2 += v1 * bf_lo(x1.y); a3 += v1 * bf_hi(x1.y);
            a0 += v2 * bf_lo(x2.x); a1 += v2 * bf_hi(x2.x);
            a2 += v2 * bf_lo(x2.y); a3 += v2 * bf_hi(x2.y);
            a0 += v3 * bf_lo(x3.x); a1 += v3 * bf_hi(x3.x);
            a2 += v3 * bf_lo(x3.y); a3 += v3 * bf_hi(x3.y);
        }
    }

    float o0 = scale * a0, o1 = scale * a1, o2 = scale * a2, o3 = scale * a3;
    if (xsub) {
        uint2 sx = xsub[(size_t)row * ROW_U2 + col2];
        o0 -= bf_lo(sx.x); o1 -= bf_hi(sx.x);
        o2 -= bf_lo(sx.y); o3 -= bf_hi(sx.y);
    }
    uint2 o;
    o.x = pack2(o0, o1);
    o.y = pack2(o2, o3);
    xout[(size_t)row * ROW_U2 + col2] = o;
}

// ---------------------------------------------------------------------------
// k_combine (MFMA): out[b,n,u] = bias[u] + sum_k A[(b,n), k] * Wp[k, u]
// with k = mat*64 + i, A[(b,n), k] = T_mat[n, b*64+i] (bf16, contiguous in i).
// Block = 4 waves; wave w owns 16 nodes x 64 units, loops b = 0..7.
// W transposed to LDS as bf16 [u][k] (k padded 192->200); A frags load
// direct from L2-hot x arrays as 16B short8.
// ---------------------------------------------------------------------------
__global__ __launch_bounds__(256) void k_combine(const uint* __restrict__ x0,
                                                 const uint* __restrict__ x1,
                                                 const uint* __restrict__ x2,
                                                 const float* __restrict__ W,
                                                 const float* __restrict__ bias,
                                                 float* __restrict__ out) {
    __shared__ unsigned short sWt[64][200];    // [u][k] bf16, pad 192->200 (25.6 KB)
    int t = threadIdx.x;
    for (int e = t; e < 192 * 64; e += 256) {
        int f = e >> 6;                        // fan_in row = i*3 + m
        int u = e & 63;
        int i = f / 3;
        int m = f - 3 * i;
        sWt[u][m * 64 + i] = (unsigned short)f2bf_bits(W[e]);
    }
    __syncthreads();

    int wave = t >> 6, lane = t & 63;
    int mrow = lane & 15, quad = lane >> 4;
    int n0   = blockIdx.x * 64 + wave * 16;

    // B fragments: 6 k-blocks x 4 u-tiles, loaded once, reused for all 8 b.
    short8 bfrag[6][4];
#pragma unroll
    for (int kb = 0; kb < 6; ++kb)
#pragma unroll
        for (int ut = 0; ut < 4; ++ut)
            bfrag[kb][ut] = *(const short8*)&sWt[ut * 16 + mrow][kb * 32 + quad * 8];

    float bv[4];
#pragma unroll
    for (int ut = 0; ut < 4; ++ut) bv[ut] = bias[ut * 16 + mrow];

    const uint* xs[3] = {x0, x1, x2};
    int an = n0 + mrow;                        // node this lane's A row covers

    for (int b = 0; b < 8; ++b) {
        float4v acc[4];
#pragma unroll
        for (int ut = 0; ut < 4; ++ut) acc[ut] = (float4v){0.f, 0.f, 0.f, 0.f};

#pragma unroll
        for (int kb = 0; kb < 6; ++kb) {
            int mat = kb >> 1;
            int i0  = (kb & 1) * 32;
            const short8* ap =
                (const short8*)(xs[mat] + (size_t)an * ROW_U + b * 32 + i0 / 2 + quad * 4);
            short8 af = *ap;
#pragma unroll
            for (int ut = 0; ut < 4; ++ut)
                acc[ut] = __builtin_amdgcn_mfma_f32_16x16x32_bf16(af, bfrag[kb][ut],
                                                                  acc[ut], 0, 0, 0);
        }

#pragma unroll
        for (int ut = 0; ut < 4; ++ut) {
            int u = ut * 16 + mrow;
#pragma unroll
            for (int r = 0; r < 4; ++r) {
                int n = n0 + quad * 4 + r;
                if (n < N_NODES)
                    out[((size_t)b * N_NODES + n) * UNITS + u] = acc[ut][r] + bv[ut];
            }
        }
    }
}

// ---------------------------------------------------------------------------
extern "C" void kernel_launch(void* const* d_in, const int* in_sizes, int n_in,
                              void* d_out, int out_size, void* d_ws, size_t ws_size,
                              hipStream_t stream) {
    const float* inputs = (const float*)d_in[0];
    const int*   rows   = (const int*)d_in[1];
    const int*   cols   = (const int*)d_in[2];
    const float* vals   = (const float*)d_in[3];
    const float* W      = (const float*)d_in[4];
    const float* bias   = (const float*)d_in[5];
    float*       out    = (float*)d_out;
    int nnz = in_sizes[1];

    char* p = (char*)d_ws;
    auto alloc = [&](size_t bytes) {
        char* r = p;
        p += (bytes + 255) & ~(size_t)255;
        return r;
    };
    uint*  x0      = (uint*)alloc(sizeof(uint) * (size_t)N_NODES * ROW_U);
    uint*  x1      = (uint*)alloc(sizeof(uint) * (size_t)N_NODES * ROW_U);
    uint*  x2      = (uint*)alloc(sizeof(uint) * (size_t)N_NODES * ROW_U);
    int*   row_ptr = (int*)alloc(sizeof(int) * (N_NODES + 1));
    int*   cursor  = (int*)alloc(sizeof(int) * N_NODES);
    int*   cols_s  = (int*)alloc(sizeof(int) * (size_t)nnz);
    float* vals_s  = (float*)alloc(sizeof(float) * (size_t)nnz);

    k_transpose<<<N_NODES, 256, 0, stream>>>((const float2*)inputs, x0, cursor);
    k_hist<<<(nnz + 255) / 256, 256, 0, stream>>>(rows, cursor, nnz);
    k_scan<<<1, 256, 0, stream>>>(cursor, row_ptr, N_NODES);
    k_scatter<<<(nnz + 255) / 256, 256, 0, stream>>>(rows, cols, vals, row_ptr, cursor,
                                                     cols_s, vals_s, nnz);
    dim3 sgrid(N_NODES / 4, 2);
    k_spmm<<<sgrid, 256, 0, stream>>>(row_ptr, cols_s, vals_s, (const uint2*)x0,
                                      (uint2*)x1, nullptr, 1.0f);
    k_spmm<<<sgrid, 256, 0, stream>>>(row_ptr, cols_s, vals_s, (const uint2*)x1,
                                      (uint2*)x2, (const uint2*)x0, 2.0f);
    k_combine<<<(N_NODES + 63) / 64, 256, 0, stream>>>(x0, x1, x2, W, bias, out);
}

// Round 5
// 222.170 us; speedup vs baseline: 1.3179x; 1.0045x over previous
//
#include <hip/hip_runtime.h>

#define N_NODES 10000
#define BATCH   8
#define IN_SZ   64
#define UNITS   64
#define WIDTH   512            // IN_SZ * BATCH (bf16 elements per node row)
#define ROW_U   256            // uints per bf16 row (512 bf16)

typedef unsigned int uint;
typedef __attribute__((ext_vector_type(8))) short short8;
typedef __attribute__((ext_vector_type(4))) float float4v;

// ---- bf16 helpers (RNE) ----------------------------------------------------
__device__ inline float bf_lo(uint u) { return __uint_as_float(u << 16); }
__device__ inline float bf_hi(uint u) { return __uint_as_float(u & 0xFFFF0000u); }
__device__ inline uint  f2bf_bits(float f) {
    uint u = __float_as_uint(f);
    uint r = ((u >> 16) & 1u) + 0x7FFFu;
    return (u + r) >> 16;
}
__device__ inline uint pack2(float a, float b) {
    return f2bf_bits(a) | (f2bf_bits(b) << 16);
}

// ---------------------------------------------------------------------------
// k_transpose_hist: in[b, n*64+i] (fp32) -> x0[n, b*64+i] (bf16) — pure
// coalesced copy. Also does the CSR row histogram (counts pre-zeroed by
// hipMemsetAsync) using the same grid's first nnz threads.
// ---------------------------------------------------------------------------
__global__ __launch_bounds__(256) void k_transpose_hist(const float2* __restrict__ in2,
                                                        uint* __restrict__ x0,
                                                        const int* __restrict__ rows,
                                                        int* __restrict__ counts,
                                                        int nnz) {
    int gid = blockIdx.x * 256 + threadIdx.x;      // uint index, 2,560,000 total
    if (gid < nnz) atomicAdd(&counts[rows[gid]], 1);
    int n  = gid >> 8;          // /256 uints per row
    int b  = (gid >> 5) & 7;    // 32 uints per (n,b) chunk
    int iu = gid & 31;
    float2 v = in2[(size_t)b * (N_NODES * 32) + (size_t)n * 32 + iu];
    x0[gid] = pack2(v.x, v.y);
}

// ---------------------------------------------------------------------------
// k_scan: single block, 256 threads, serial chunk + wave shfl-scan.
// Zeroes counts for reuse as scatter cursors.
// ---------------------------------------------------------------------------
#define CHUNK 40
__global__ __launch_bounds__(256) void k_scan(int* __restrict__ counts,
                                              int* __restrict__ row_ptr, int n) {
    __shared__ int wsum[4];
    int t    = threadIdx.x;
    int base = t * CHUNK;
    int local[CHUNK];
    int tot = 0;
#pragma unroll
    for (int j = 0; j < CHUNK; ++j) {
        int idx = base + j;
        int v   = (idx < n) ? counts[idx] : 0;
        if (idx < n) counts[idx] = 0;
        local[j] = v;
        tot += v;
    }
    int lane = t & 63, w = t >> 6;
    int s = tot;
#pragma unroll
    for (int off = 1; off < 64; off <<= 1) {
        int nv = __shfl_up(s, off);
        if (lane >= off) s += nv;
    }
    if (lane == 63) wsum[w] = s;
    __syncthreads();
    int woff = 0;
    for (int k = 0; k < 4; ++k) if (k < w) woff += wsum[k];
    int run = woff + s - tot;
#pragma unroll
    for (int j = 0; j < CHUNK; ++j) {
        int idx = base + j;
        if (idx < n) row_ptr[idx] = run;
        run += local[j];
    }
    if (t == 255) row_ptr[n] = woff + s;
}

// ---------------------------------------------------------------------------
// k_scatter: scatter COO edges into CSR order as packed (col, val) uint2.
// ---------------------------------------------------------------------------
__global__ __launch_bounds__(256) void k_scatter(const int* __restrict__ rows,
                                                 const int* __restrict__ cols,
                                                 const float* __restrict__ vals,
                                                 const int* __restrict__ row_ptr,
                                                 int* __restrict__ cursor,
                                                 uint2* __restrict__ edges, int nnz) {
    int e = blockIdx.x * 256 + threadIdx.x;
    if (e >= nnz) return;
    int r   = rows[e];
    int pos = row_ptr[r] + atomicAdd(&cursor[r], 1);
    uint2 ev;
    ev.x = (uint)cols[e];
    ev.y = __float_as_uint(vals[e]);
    edges[pos] = ev;
}

// ---------------------------------------------------------------------------
// k_spmm: one WAVE per (row, column-quarter). Lane owns one uint (2 bf16
// cols); quarter working set = 10000*256B = 2.5 MB -> resident in each XCD's
// 4 MiB L2 (proven in round 3: FETCH 55 MB). Edge list zero-padded to
// groups of 8: 8 independent global_load_dword in flight; (col,val) pairs
// come from one dwordx2 per lane per 64 edges, broadcast via readlane.
// ---------------------------------------------------------------------------
__global__ __launch_bounds__(256) void k_spmm(const int* __restrict__ row_ptr,
                                              const uint2* __restrict__ edges,
                                              const uint* __restrict__ xin,
                                              uint* __restrict__ xout,
                                              const uint* __restrict__ xsub,
                                              float scale) {
    int wave  = threadIdx.x >> 6;
    int lane  = threadIdx.x & 63;
    int row   = blockIdx.x * 4 + wave;
    int col_u = blockIdx.y * 64 + lane;        // uint column (of 256 per row)

    int start = row_ptr[row];
    int end   = row_ptr[row + 1];
    float alo = 0.f, ahi = 0.f;

    for (int base = start; base < end; base += 64) {
        int e = base + lane;
        uint2 ev = make_uint2(0u, 0u);
        if (e < end) ev = edges[e];            // pad: col=0, val=0
        int cnt = min(64, end - base);
        cnt = (cnt + 7) & ~7;                  // zero-padded groups of 8
        for (int j0 = 0; j0 < cnt; j0 += 8) {
            int   c[8];
            float v[8];
            uint  x[8];
#pragma unroll
            for (int j = 0; j < 8; ++j) {
                c[j] = __builtin_amdgcn_readlane((int)ev.x, j0 + j);
                v[j] = __uint_as_float(__builtin_amdgcn_readlane((int)ev.y, j0 + j));
            }
#pragma unroll
            for (int j = 0; j < 8; ++j)
                x[j] = xin[(size_t)c[j] * ROW_U + col_u];
#pragma unroll
            for (int j = 0; j < 8; ++j) {
                alo += v[j] * bf_lo(x[j]);
                ahi += v[j] * bf_hi(x[j]);
            }
        }
    }

    float olo = scale * alo, ohi = scale * ahi;
    if (xsub) {
        uint sx = xsub[(size_t)row * ROW_U + col_u];
        olo -= bf_lo(sx);
        ohi -= bf_hi(sx);
    }
    xout[(size_t)row * ROW_U + col_u] = pack2(olo, ohi);
}

// ---------------------------------------------------------------------------
// k_combine (MFMA): out[b,n,u] = bias[u] + sum_k A[(b,n), k] * Wp[k, u]
// with k = mat*64 + i, A[(b,n), k] = T_mat[n, b*64+i] (bf16, contiguous in i).
// Block = 4 waves; wave w owns 16 nodes x 64 units, loops b = 0..7.
// W transposed to LDS as bf16 [u][k] (k padded 192->200); A frags load
// direct from L2-hot x arrays as 16B short8.
// ---------------------------------------------------------------------------
__global__ __launch_bounds__(256) void k_combine(const uint* __restrict__ x0,
                                                 const uint* __restrict__ x1,
                                                 const uint* __restrict__ x2,
                                                 const float* __restrict__ W,
                                                 const float* __restrict__ bias,
                                                 float* __restrict__ out) {
    __shared__ unsigned short sWt[64][200];    // [u][k] bf16, pad 192->200 (25.6 KB)
    int t = threadIdx.x;
    for (int e = t; e < 192 * 64; e += 256) {
        int f = e >> 6;                        // fan_in row = i*3 + m
        int u = e & 63;
        int i = f / 3;
        int m = f - 3 * i;
        sWt[u][m * 64 + i] = (unsigned short)f2bf_bits(W[e]);
    }
    __syncthreads();

    int wave = t >> 6, lane = t & 63;
    int mrow = lane & 15, quad = lane >> 4;
    int n0   = blockIdx.x * 64 + wave * 16;

    // B fragments: 6 k-blocks x 4 u-tiles, loaded once, reused for all 8 b.
    short8 bfrag[6][4];
#pragma unroll
    for (int kb = 0; kb < 6; ++kb)
#pragma unroll
        for (int ut = 0; ut < 4; ++ut)
            bfrag[kb][ut] = *(const short8*)&sWt[ut * 16 + mrow][kb * 32 + quad * 8];

    float bv[4];
#pragma unroll
    for (int ut = 0; ut < 4; ++ut) bv[ut] = bias[ut * 16 + mrow];

    const uint* xs[3] = {x0, x1, x2};
    int an = n0 + mrow;                        // node this lane's A row covers

    for (int b = 0; b < 8; ++b) {
        float4v acc[4];
#pragma unroll
        for (int ut = 0; ut < 4; ++ut) acc[ut] = (float4v){0.f, 0.f, 0.f, 0.f};

#pragma unroll
        for (int kb = 0; kb < 6; ++kb) {
            int mat = kb >> 1;
            int i0  = (kb & 1) * 32;
            const short8* ap =
                (const short8*)(xs[mat] + (size_t)an * ROW_U + b * 32 + i0 / 2 + quad * 4);
            short8 af = *ap;
#pragma unroll
            for (int ut = 0; ut < 4; ++ut)
                acc[ut] = __builtin_amdgcn_mfma_f32_16x16x32_bf16(af, bfrag[kb][ut],
                                                                  acc[ut], 0, 0, 0);
        }

#pragma unroll
        for (int ut = 0; ut < 4; ++ut) {
            int u = ut * 16 + mrow;
#pragma unroll
            for (int r = 0; r < 4; ++r) {
                int n = n0 + quad * 4 + r;
                if (n < N_NODES)
                    out[((size_t)b * N_NODES + n) * UNITS + u] = acc[ut][r] + bv[ut];
            }
        }
    }
}

// ---------------------------------------------------------------------------
extern "C" void kernel_launch(void* const* d_in, const int* in_sizes, int n_in,
                              void* d_out, int out_size, void* d_ws, size_t ws_size,
                              hipStream_t stream) {
    const float* inputs = (const float*)d_in[0];
    const int*   rows   = (const int*)d_in[1];
    const int*   cols   = (const int*)d_in[2];
    const float* vals   = (const float*)d_in[3];
    const float* W      = (const float*)d_in[4];
    const float* bias   = (const float*)d_in[5];
    float*       out    = (float*)d_out;
    int nnz = in_sizes[1];

    char* p = (char*)d_ws;
    auto alloc = [&](size_t bytes) {
        char* r = p;
        p += (bytes + 255) & ~(size_t)255;
        return r;
    };
    uint*  x0      = (uint*)alloc(sizeof(uint) * (size_t)N_NODES * ROW_U);
    uint*  x1      = (uint*)alloc(sizeof(uint) * (size_t)N_NODES * ROW_U);
    uint*  x2      = (uint*)alloc(sizeof(uint) * (size_t)N_NODES * ROW_U);
    int*   row_ptr = (int*)alloc(sizeof(int) * (N_NODES + 1));
    int*   cursor  = (int*)alloc(sizeof(int) * N_NODES);
    uint2* edges   = (uint2*)alloc(sizeof(uint2) * (size_t)nnz);

    hipMemsetAsync(cursor, 0, sizeof(int) * N_NODES, stream);
    k_transpose_hist<<<N_NODES, 256, 0, stream>>>((const float2*)inputs, x0, rows,
                                                  cursor, nnz);
    k_scan<<<1, 256, 0, stream>>>(cursor, row_ptr, N_NODES);
    k_scatter<<<(nnz + 255) / 256, 256, 0, stream>>>(rows, cols, vals, row_ptr, cursor,
                                                     edges, nnz);
    dim3 sgrid(N_NODES / 4, 4);
    k_spmm<<<sgrid, 256, 0, stream>>>(row_ptr, edges, x0, x1, nullptr, 1.0f);
    k_spmm<<<sgrid, 256, 0, stream>>>(row_ptr, edges, x1, x2, x0, 2.0f);
    k_combine<<<(N_NODES + 63) / 64, 256, 0, stream>>>(x0, x1, x2, W, bias, out);
}